// Round 10
// baseline (99.646 us; speedup 1.0000x reference)
//
#include <hip/hip_runtime.h>

// BPNet fused forward: E=16384, ORDER=3, D=13, RANK=128, NUM_PARAMS=4.
// R9 = R7 (best measured: 80.9 us) + staging loads issued before the
// metadata/gather chain (overlap global latency with the pre-barrier copy).
// Tables f16-packed (v_dot2_f32_f16), stage-1 tables split A/B so lane
// reads 4g..4g+3 (all 32 banks, 2-way = free). 512-thread blocks x 4
// edges/wave, 2 blocks/CU, facts stay in registers, DPP row_sum16
// reduction, one atomic per edge-slot. Out-zeroing folded into pack.
// NUM_ITERS loop in reference is idempotent -> one iteration.

#define DD 13
#define OD 3
#define NP 4
#define RK 128

typedef unsigned int uint;
typedef _Float16 h2 __attribute__((ext_vector_type(2)));

// LDS/ws layout (dword offsets)
#define W2H_OFF 0                    // [12][13][64] h2: dword c -> ranks (2c,2c+1), dim dd
#define W2H_N   (12 * 13 * 64)       // 9984
#define W1A_OFF (W2H_OFF + W2H_N)    // [4][7][64] h2: c=4g+k -> rank 8g+k, d-pair p
#define W1A_N   (4 * 7 * 64)         // 1792
#define W1B_OFF (W1A_OFF + W1A_N)    // [4][7][64]: rank 8g+4+k
#define W1B_N   (4 * 7 * 64)         // 1792
#define B1A_OFF (W1B_OFF + W1B_N)    // [4][64] f32: c=4g+k -> bias rank 8g+k
#define B1A_N   (4 * 64)             // 256
#define B1B_OFF (B1A_OFF + B1A_N)    // [4][64] f32: rank 8g+4+k
#define B1B_N   (4 * 64)             // 256
#define HOB_OFF (B1B_OFF + B1B_N)    // [12][16] f32 (dd>=13 zeroed)
#define HOB_N   (12 * 16)            // 192
#define TAB_N   (HOB_OFF + HOB_N)    // 14272 dwords = 57088 B
#define NROW_OFF TAB_N               // [8 waves][12 rows][8] h2 node d-pairs
#define NROW_N  (8 * 12 * 8)         // 768
#define SH_N    (TAB_N + NROW_N)     // 15040 dwords = 60160 B

__device__ __forceinline__ uint pk(float lo, float hi) {
    return __builtin_bit_cast(uint, __builtin_amdgcn_cvt_pkrtz(lo, hi));
}
__device__ __forceinline__ h2 ash2(uint w) { return __builtin_bit_cast(h2, w); }

template <int CTRL>
__device__ __forceinline__ float dpp_add(float x) {
    int p = __builtin_amdgcn_update_dpp(0, __float_as_int(x), CTRL, 0xF, 0xF, false);
    return x + __int_as_float(p);
}
__device__ __forceinline__ float row_sum16(float x) {
    x = dpp_add<0xB1>(x);   // quad_perm xor1
    x = dpp_add<0x4E>(x);   // quad_perm xor2
    x = dpp_add<0x141>(x);  // row_half_mirror
    x = dpp_add<0x140>(x);  // row_mirror -> lane has its row-of-16 sum
    return x;
}

__global__ __launch_bounds__(256) void bpnet_pack(
    const float* __restrict__ bp_params,  // [4,13,128]
    const float* __restrict__ bp_bias,    // [4,1,128]
    const float* __restrict__ ho_params,  // [3,4,128,13]
    const float* __restrict__ ho_bias,    // [3,4,1,13]
    uint* __restrict__ ws,
    uint* __restrict__ outz, int out_n)   // also zero the output buffer
{
    const int tid = blockIdx.x * 256 + threadIdx.x;
    const int nthr = gridDim.x * 256;

    // ---- zero out (grid-stride uint4) ----
    const int n4 = out_n >> 2;
    for (int k = tid; k < n4; k += nthr) ((uint4*)outz)[k] = uint4{0, 0, 0, 0};
    if (tid < (out_n & 3)) outz[(n4 << 2) + tid] = 0;

    // ---- pack tables ----
    if (tid < W1A_OFF) {                       // W2H [it][dd][c]
        const int c = tid & 63, q = tid >> 6;
        const int dd = q % 13, it = q / 13;
        ws[tid] = pk(ho_params[(size_t)(it * RK + 2 * c) * DD + dd],
                     ho_params[(size_t)(it * RK + 2 * c + 1) * DD + dd]);
    } else if (tid < W1B_OFF) {                // W1A [ty][p][c], rank 8g+k
        const int j = tid - W1A_OFF;
        const int c = j & 63, q = j >> 6;
        const int p = q % 7, ty = q / 7;
        const int r = 8 * (c >> 2) + (c & 3);
        const float a = bp_params[(ty * DD + 2 * p) * RK + r];
        const float b = (2 * p + 1 < DD) ? bp_params[(ty * DD + 2 * p + 1) * RK + r] : 0.f;
        ws[tid] = pk(a, b);
    } else if (tid < B1A_OFF) {                // W1B [ty][p][c], rank 8g+4+k
        const int j = tid - W1B_OFF;
        const int c = j & 63, q = j >> 6;
        const int p = q % 7, ty = q / 7;
        const int r = 8 * (c >> 2) + 4 + (c & 3);
        const float a = bp_params[(ty * DD + 2 * p) * RK + r];
        const float b = (2 * p + 1 < DD) ? bp_params[(ty * DD + 2 * p + 1) * RK + r] : 0.f;
        ws[tid] = pk(a, b);
    } else if (tid < B1B_OFF) {                // B1A f32
        const int j = tid - B1A_OFF;
        const int c = j & 63, ty = j >> 6;
        ((float*)ws)[tid] = bp_bias[ty * RK + 8 * (c >> 2) + (c & 3)];
    } else if (tid < HOB_OFF) {                // B1B f32
        const int j = tid - B1B_OFF;
        const int c = j & 63, ty = j >> 6;
        ((float*)ws)[tid] = bp_bias[ty * RK + 8 * (c >> 2) + 4 + (c & 3)];
    } else if (tid < TAB_N) {                  // HOB [it][16]
        const int j = tid - HOB_OFF;
        const int dd = j & 15, it = j >> 4;
        ((float*)ws)[tid] = (dd < DD) ? ho_bias[it * DD + dd] : 0.f;
    }
}

__global__ __launch_bounds__(512, 4) void bpnet_fused(
    const float* __restrict__ nodes,      // [N, 13]
    const int*   __restrict__ edges,      // [E, 3]
    const int*   __restrict__ edge_types, // [E, 3]
    const uint*  __restrict__ tab,        // packed tables (TAB_N dwords)
    float*       __restrict__ out)        // [N, 13] (pre-zeroed)
{
    __shared__ __align__(16) uint sh[SH_N];
    const int tid  = threadIdx.x;
    const int lane = tid & 63;
    const int wv   = tid >> 6;        // 0..7
    const int e4   = lane >> 4;       // edge within wave's 4
    const int g    = lane & 15;       // rank octet 8g..8g+7
    const int eb   = (blockIdx.x * 8 + wv) * 4;

    // ---- issue the block-wide staging loads FIRST (their latency overlaps
    // the metadata -> shfl -> gather dependency chain below; the barrier
    // waits on the slowest wave's staging writes) ----
    uint4 stg[7];
    int  stg_k[7], nstg = 0;
#pragma unroll
    for (int c = 0; c < 7; ++c) {
        const int k4 = c * 512 + tid;
        if (k4 < TAB_N / 4) { stg[nstg] = ((const uint4*)tab)[k4]; stg_k[nstg++] = k4; }
    }

    // ---- wave metadata ----
    int ev = 0, tv = 0;
    if (lane < 12) {
        ev = edges[eb * OD + lane];
        tv = edge_types[eb * OD + lane];
    }

    // ---- gather 12 node rows as packed h2 d-pairs into per-wave LDS ----
    uint* mynr = sh + NROW_OFF + wv * 96;
#pragma unroll
    for (int pass = 0; pass < 2; ++pass) {
        const int idx = pass * 64 + lane;
        if (idx < 96) {
            const int r = idx >> 3, p = idx & 7;
            const int nr_ = __shfl(ev, r, 64);
            uint v = 0;
            if (p < 6)       v = pk(nodes[(size_t)nr_ * DD + 2 * p],
                                    nodes[(size_t)nr_ * DD + 2 * p + 1]);
            else if (p == 6) v = pk(nodes[(size_t)nr_ * DD + 12], 0.f);
            mynr[r * 8 + p] = v;
        }
    }

    // ---- commit staged tables to LDS ----
    for (int c = 0; c < nstg; ++c) ((uint4*)sh)[stg_k[c]] = stg[c];
    __syncthreads();

    int tg[OD], et[OD];
#pragma unroll
    for (int i = 0; i < OD; ++i) {
        tg[i] = __shfl(ev, e4 * OD + i, 64);
        et[i] = __shfl(tv, e4 * OD + i, 64);
    }

    // ---- stage 1: t[o][0..7] for ranks 8g..8g+7 of edge e4 ----
    float t[OD][8];
#pragma unroll
    for (int o = 0; o < OD; ++o) {
        const uint* nh = mynr + (e4 * OD + o) * 8;
        const uint4 n0 = *(const uint4*)(nh);       // d-pairs 0..3 (broadcast)
        const uint4 n1 = *(const uint4*)(nh + 4);   // d-pairs 4..6 (+pad)
        const float4 b0 = *(const float4*)((const float*)(sh + B1A_OFF) + et[o] * 64 + 4 * g);
        const float4 b1 = *(const float4*)((const float*)(sh + B1B_OFF) + et[o] * 64 + 4 * g);
        float s[8] = {b0.x, b0.y, b0.z, b0.w, b1.x, b1.y, b1.z, b1.w};
        const uint* wa = sh + W1A_OFF + (et[o] * 7) * 64 + 4 * g;
        const uint* wb = sh + W1B_OFF + (et[o] * 7) * 64 + 4 * g;
#define S1(p, nv) { const uint4 wA = *(const uint4*)(wa + (p) * 64);          \
                    const uint4 wB = *(const uint4*)(wb + (p) * 64);          \
            const h2 nn = ash2(nv);                                           \
            s[0] = __builtin_amdgcn_fdot2(nn, ash2(wA.x), s[0], false);       \
            s[1] = __builtin_amdgcn_fdot2(nn, ash2(wA.y), s[1], false);       \
            s[2] = __builtin_amdgcn_fdot2(nn, ash2(wA.z), s[2], false);       \
            s[3] = __builtin_amdgcn_fdot2(nn, ash2(wA.w), s[3], false);       \
            s[4] = __builtin_amdgcn_fdot2(nn, ash2(wB.x), s[4], false);       \
            s[5] = __builtin_amdgcn_fdot2(nn, ash2(wB.y), s[5], false);       \
            s[6] = __builtin_amdgcn_fdot2(nn, ash2(wB.z), s[6], false);       \
            s[7] = __builtin_amdgcn_fdot2(nn, ash2(wB.w), s[7], false); }
        S1(0, n0.x) S1(1, n0.y) S1(2, n0.z) S1(3, n0.w)
        S1(4, n1.x) S1(5, n1.y) S1(6, n1.z)
#undef S1
#pragma unroll
        for (int r = 0; r < 8; ++r) t[o][r] = fmaxf(s[r], 0.f);
    }

    // ---- stage 2: facts in registers -> h2, dot2 vs W2H rows ----
#pragma unroll
    for (int i = 0; i < OD; ++i) {
        const int j = (i + 1) % OD, k = (i + 2) % OD;
        uint fh[4];
#pragma unroll
        for (int r = 0; r < 4; ++r)
            fh[r] = pk(t[j][2 * r] * t[k][2 * r], t[j][2 * r + 1] * t[k][2 * r + 1]);
        const int it = i * NP + et[i];
        const uint* wb2 = sh + W2H_OFF + (it * DD) * 64 + 4 * g;
        float c[DD];
#pragma unroll
        for (int dd = 0; dd < DD; ++dd) {
            const uint4 w = *(const uint4*)(wb2 + dd * 64);
            float a = __builtin_amdgcn_fdot2(ash2(fh[0]), ash2(w.x), 0.f, false);
            a = __builtin_amdgcn_fdot2(ash2(fh[1]), ash2(w.y), a, false);
            a = __builtin_amdgcn_fdot2(ash2(fh[2]), ash2(w.z), a, false);
            a = __builtin_amdgcn_fdot2(ash2(fh[3]), ash2(w.w), a, false);
            c[dd] = a;
        }
#pragma unroll
        for (int dd = 0; dd < DD; ++dd) c[dd] = row_sum16(c[dd]);
        float q = c[0];
#pragma unroll
        for (int dd = 1; dd < DD; ++dd) q = (g == dd) ? c[dd] : q;
        q += ((const float*)(sh + HOB_OFF))[it * 16 + g];
        if (g < DD) atomicAdd(out + (size_t)tg[i] * DD + g, q);
    }
}

extern "C" void kernel_launch(void* const* d_in, const int* in_sizes, int n_in,
                              void* d_out, int out_size, void* d_ws, size_t ws_size,
                              hipStream_t stream) {
    const float* nodes      = (const float*)d_in[0];
    const float* bp_params  = (const float*)d_in[1];
    const float* bp_bias    = (const float*)d_in[2];
    const float* ho_params  = (const float*)d_in[3];
    const float* ho_bias    = (const float*)d_in[4];
    const int*   edges      = (const int*)d_in[5];
    const int*   edge_types = (const int*)d_in[6];
    float* out = (float*)d_out;
    uint*  ws  = (uint*)d_ws;

    const int E = in_sizes[5] / OD;   // 16384

    // pack kernel also zeroes out (poisoned 0xAA before every timed call)
    bpnet_pack<<<(TAB_N + 255) / 256, 256, 0, stream>>>(
        bp_params, bp_bias, ho_params, ho_bias, ws, (uint*)out, out_size);

    // E/32 = 512 blocks x 8 waves x 4 edges = 16384
    bpnet_fused<<<E / 32, 512, 0, stream>>>(nodes, edges, edge_types, ws, out);
}

// Round 11
// 80.229 us; speedup vs baseline: 1.2420x; 1.2420x over previous
//
#include <hip/hip_runtime.h>

// BPNet fused forward: E=16384, ORDER=3, D=13, RANK=128, NUM_PARAMS=4.
// R10 = exact revert to R7 (best measured: 80.9 us).
// (1) stage-1 LDS tables split A/B so lane reads 4g..4g+3 (all 32 banks,
// 2-way = free); (2) out-zeroing folded into pack kernel; (3) node gather
// above table staging. Tables f16-packed (v_dot2_f32_f16), 512-thread
// blocks x 4 edges/wave, 2 blocks/CU resident, facts stay in registers,
// DPP row_sum16 reduction, one atomic per edge-slot.
// NUM_ITERS loop in reference is idempotent -> one iteration.

#define DD 13
#define OD 3
#define NP 4
#define RK 128

typedef unsigned int uint;
typedef _Float16 h2 __attribute__((ext_vector_type(2)));

// LDS/ws layout (dword offsets)
#define W2H_OFF 0                    // [12][13][64] h2: dword c -> ranks (2c,2c+1), dim dd
#define W2H_N   (12 * 13 * 64)       // 9984
#define W1A_OFF (W2H_OFF + W2H_N)    // [4][7][64] h2: c=4g+k -> rank 8g+k, d-pair p
#define W1A_N   (4 * 7 * 64)         // 1792
#define W1B_OFF (W1A_OFF + W1A_N)    // [4][7][64]: rank 8g+4+k
#define W1B_N   (4 * 7 * 64)         // 1792
#define B1A_OFF (W1B_OFF + W1B_N)    // [4][64] f32: c=4g+k -> bias rank 8g+k
#define B1A_N   (4 * 64)             // 256
#define B1B_OFF (B1A_OFF + B1A_N)    // [4][64] f32: rank 8g+4+k
#define B1B_N   (4 * 64)             // 256
#define HOB_OFF (B1B_OFF + B1B_N)    // [12][16] f32 (dd>=13 zeroed)
#define HOB_N   (12 * 16)            // 192
#define TAB_N   (HOB_OFF + HOB_N)    // 14272 dwords = 57088 B
#define NROW_OFF TAB_N               // [8 waves][12 rows][8] h2 node d-pairs
#define NROW_N  (8 * 12 * 8)         // 768
#define SH_N    (TAB_N + NROW_N)     // 15040 dwords = 60160 B

__device__ __forceinline__ uint pk(float lo, float hi) {
    return __builtin_bit_cast(uint, __builtin_amdgcn_cvt_pkrtz(lo, hi));
}
__device__ __forceinline__ h2 ash2(uint w) { return __builtin_bit_cast(h2, w); }

template <int CTRL>
__device__ __forceinline__ float dpp_add(float x) {
    int p = __builtin_amdgcn_update_dpp(0, __float_as_int(x), CTRL, 0xF, 0xF, false);
    return x + __int_as_float(p);
}
__device__ __forceinline__ float row_sum16(float x) {
    x = dpp_add<0xB1>(x);   // quad_perm xor1
    x = dpp_add<0x4E>(x);   // quad_perm xor2
    x = dpp_add<0x141>(x);  // row_half_mirror
    x = dpp_add<0x140>(x);  // row_mirror -> lane has its row-of-16 sum
    return x;
}

__global__ __launch_bounds__(256) void bpnet_pack(
    const float* __restrict__ bp_params,  // [4,13,128]
    const float* __restrict__ bp_bias,    // [4,1,128]
    const float* __restrict__ ho_params,  // [3,4,128,13]
    const float* __restrict__ ho_bias,    // [3,4,1,13]
    uint* __restrict__ ws,
    uint* __restrict__ outz, int out_n)   // also zero the output buffer
{
    const int tid = blockIdx.x * 256 + threadIdx.x;
    const int nthr = gridDim.x * 256;

    // ---- zero out (grid-stride uint4) ----
    const int n4 = out_n >> 2;
    for (int k = tid; k < n4; k += nthr) ((uint4*)outz)[k] = uint4{0, 0, 0, 0};
    if (tid < (out_n & 3)) outz[(n4 << 2) + tid] = 0;

    // ---- pack tables ----
    if (tid < W1A_OFF) {                       // W2H [it][dd][c]
        const int c = tid & 63, q = tid >> 6;
        const int dd = q % 13, it = q / 13;
        ws[tid] = pk(ho_params[(size_t)(it * RK + 2 * c) * DD + dd],
                     ho_params[(size_t)(it * RK + 2 * c + 1) * DD + dd]);
    } else if (tid < W1B_OFF) {                // W1A [ty][p][c], rank 8g+k
        const int j = tid - W1A_OFF;
        const int c = j & 63, q = j >> 6;
        const int p = q % 7, ty = q / 7;
        const int r = 8 * (c >> 2) + (c & 3);
        const float a = bp_params[(ty * DD + 2 * p) * RK + r];
        const float b = (2 * p + 1 < DD) ? bp_params[(ty * DD + 2 * p + 1) * RK + r] : 0.f;
        ws[tid] = pk(a, b);
    } else if (tid < B1A_OFF) {                // W1B [ty][p][c], rank 8g+4+k
        const int j = tid - W1B_OFF;
        const int c = j & 63, q = j >> 6;
        const int p = q % 7, ty = q / 7;
        const int r = 8 * (c >> 2) + 4 + (c & 3);
        const float a = bp_params[(ty * DD + 2 * p) * RK + r];
        const float b = (2 * p + 1 < DD) ? bp_params[(ty * DD + 2 * p + 1) * RK + r] : 0.f;
        ws[tid] = pk(a, b);
    } else if (tid < B1B_OFF) {                // B1A f32
        const int j = tid - B1A_OFF;
        const int c = j & 63, ty = j >> 6;
        ((float*)ws)[tid] = bp_bias[ty * RK + 8 * (c >> 2) + (c & 3)];
    } else if (tid < HOB_OFF) {                // B1B f32
        const int j = tid - B1B_OFF;
        const int c = j & 63, ty = j >> 6;
        ((float*)ws)[tid] = bp_bias[ty * RK + 8 * (c >> 2) + 4 + (c & 3)];
    } else if (tid < TAB_N) {                  // HOB [it][16]
        const int j = tid - HOB_OFF;
        const int dd = j & 15, it = j >> 4;
        ((float*)ws)[tid] = (dd < DD) ? ho_bias[it * DD + dd] : 0.f;
    }
}

__global__ __launch_bounds__(512, 4) void bpnet_fused(
    const float* __restrict__ nodes,      // [N, 13]
    const int*   __restrict__ edges,      // [E, 3]
    const int*   __restrict__ edge_types, // [E, 3]
    const uint*  __restrict__ tab,        // packed tables (TAB_N dwords)
    float*       __restrict__ out)        // [N, 13] (pre-zeroed)
{
    __shared__ __align__(16) uint sh[SH_N];
    const int tid  = threadIdx.x;
    const int lane = tid & 63;
    const int wv   = tid >> 6;        // 0..7
    const int e4   = lane >> 4;       // edge within wave's 4
    const int g    = lane & 15;       // rank octet 8g..8g+7
    const int eb   = (blockIdx.x * 8 + wv) * 4;

    // ---- wave metadata (issued first: longest dependent chain) ----
    int ev = 0, tv = 0;
    if (lane < 12) {
        ev = edges[eb * OD + lane];
        tv = edge_types[eb * OD + lane];
    }

    // ---- gather 12 node rows as packed h2 d-pairs into per-wave LDS ----
    // (region disjoint from staged tables; overlaps the table copy below)
    uint* mynr = sh + NROW_OFF + wv * 96;
#pragma unroll
    for (int pass = 0; pass < 2; ++pass) {
        const int idx = pass * 64 + lane;
        if (idx < 96) {
            const int r = idx >> 3, p = idx & 7;
            const int nr_ = __shfl(ev, r, 64);
            uint v = 0;
            if (p < 6)       v = pk(nodes[(size_t)nr_ * DD + 2 * p],
                                    nodes[(size_t)nr_ * DD + 2 * p + 1]);
            else if (p == 6) v = pk(nodes[(size_t)nr_ * DD + 12], 0.f);
            mynr[r * 8 + p] = v;
        }
    }

    // ---- stage packed tables into LDS (flat uint4 copy) ----
    for (int k4 = tid; k4 < TAB_N / 4; k4 += 512)
        ((uint4*)sh)[k4] = ((const uint4*)tab)[k4];
    __syncthreads();

    int tg[OD], et[OD];
#pragma unroll
    for (int i = 0; i < OD; ++i) {
        tg[i] = __shfl(ev, e4 * OD + i, 64);
        et[i] = __shfl(tv, e4 * OD + i, 64);
    }

    // ---- stage 1: t[o][0..7] for ranks 8g..8g+7 of edge e4 ----
    float t[OD][8];
#pragma unroll
    for (int o = 0; o < OD; ++o) {
        const uint* nh = mynr + (e4 * OD + o) * 8;
        const uint4 n0 = *(const uint4*)(nh);       // d-pairs 0..3 (broadcast)
        const uint4 n1 = *(const uint4*)(nh + 4);   // d-pairs 4..6 (+pad)
        const float4 b0 = *(const float4*)((const float*)(sh + B1A_OFF) + et[o] * 64 + 4 * g);
        const float4 b1 = *(const float4*)((const float*)(sh + B1B_OFF) + et[o] * 64 + 4 * g);
        float s[8] = {b0.x, b0.y, b0.z, b0.w, b1.x, b1.y, b1.z, b1.w};
        const uint* wa = sh + W1A_OFF + (et[o] * 7) * 64 + 4 * g;
        const uint* wb = sh + W1B_OFF + (et[o] * 7) * 64 + 4 * g;
#define S1(p, nv) { const uint4 wA = *(const uint4*)(wa + (p) * 64);          \
                    const uint4 wB = *(const uint4*)(wb + (p) * 64);          \
            const h2 nn = ash2(nv);                                           \
            s[0] = __builtin_amdgcn_fdot2(nn, ash2(wA.x), s[0], false);       \
            s[1] = __builtin_amdgcn_fdot2(nn, ash2(wA.y), s[1], false);       \
            s[2] = __builtin_amdgcn_fdot2(nn, ash2(wA.z), s[2], false);       \
            s[3] = __builtin_amdgcn_fdot2(nn, ash2(wA.w), s[3], false);       \
            s[4] = __builtin_amdgcn_fdot2(nn, ash2(wB.x), s[4], false);       \
            s[5] = __builtin_amdgcn_fdot2(nn, ash2(wB.y), s[5], false);       \
            s[6] = __builtin_amdgcn_fdot2(nn, ash2(wB.z), s[6], false);       \
            s[7] = __builtin_amdgcn_fdot2(nn, ash2(wB.w), s[7], false); }
        S1(0, n0.x) S1(1, n0.y) S1(2, n0.z) S1(3, n0.w)
        S1(4, n1.x) S1(5, n1.y) S1(6, n1.z)
#undef S1
#pragma unroll
        for (int r = 0; r < 8; ++r) t[o][r] = fmaxf(s[r], 0.f);
    }

    // ---- stage 2: facts in registers -> h2, dot2 vs W2H rows ----
#pragma unroll
    for (int i = 0; i < OD; ++i) {
        const int j = (i + 1) % OD, k = (i + 2) % OD;
        uint fh[4];
#pragma unroll
        for (int r = 0; r < 4; ++r)
            fh[r] = pk(t[j][2 * r] * t[k][2 * r], t[j][2 * r + 1] * t[k][2 * r + 1]);
        const int it = i * NP + et[i];
        const uint* wb2 = sh + W2H_OFF + (it * DD) * 64 + 4 * g;
        float c[DD];
#pragma unroll
        for (int dd = 0; dd < DD; ++dd) {
            const uint4 w = *(const uint4*)(wb2 + dd * 64);
            float a = __builtin_amdgcn_fdot2(ash2(fh[0]), ash2(w.x), 0.f, false);
            a = __builtin_amdgcn_fdot2(ash2(fh[1]), ash2(w.y), a, false);
            a = __builtin_amdgcn_fdot2(ash2(fh[2]), ash2(w.z), a, false);
            a = __builtin_amdgcn_fdot2(ash2(fh[3]), ash2(w.w), a, false);
            c[dd] = a;
        }
#pragma unroll
        for (int dd = 0; dd < DD; ++dd) c[dd] = row_sum16(c[dd]);
        float q = c[0];
#pragma unroll
        for (int dd = 1; dd < DD; ++dd) q = (g == dd) ? c[dd] : q;
        q += ((const float*)(sh + HOB_OFF))[it * 16 + g];
        if (g < DD) atomicAdd(out + (size_t)tg[i] * DD + g, q);
    }
}

extern "C" void kernel_launch(void* const* d_in, const int* in_sizes, int n_in,
                              void* d_out, int out_size, void* d_ws, size_t ws_size,
                              hipStream_t stream) {
    const float* nodes      = (const float*)d_in[0];
    const float* bp_params  = (const float*)d_in[1];
    const float* bp_bias    = (const float*)d_in[2];
    const float* ho_params  = (const float*)d_in[3];
    const float* ho_bias    = (const float*)d_in[4];
    const int*   edges      = (const int*)d_in[5];
    const int*   edge_types = (const int*)d_in[6];
    float* out = (float*)d_out;
    uint*  ws  = (uint*)d_ws;

    const int E = in_sizes[5] / OD;   // 16384

    // pack kernel also zeroes out (poisoned 0xAA before every timed call)
    bpnet_pack<<<(TAB_N + 255) / 256, 256, 0, stream>>>(
        bp_params, bp_bias, ho_params, ho_bias, ws, (uint*)out, out_size);

    // E/32 = 512 blocks x 8 waves x 4 edges = 16384
    bpnet_fused<<<E / 32, 512, 0, stream>>>(nodes, edges, edge_types, ws, out);
}